// Round 2
// baseline (1066.239 us; speedup 1.0000x reference)
//
#include <hip/hip_runtime.h>
#include <cstdint>
#include <cstddef>

// Problem constants (match reference)
constexpr int    NN   = 2048;   // n_nodes
constexpr int    BB   = 8;      // n_samples
constexpr int    KSEL = 20;     // top-k
constexpr float  EPSV = 1e-20f; // clip epsilon
// TAU = 0.5 -> divide by tau == multiply by 2 (exact in fp32)

// ---------------------------------------------------------------------------
// Kernel 1: constant edge_index block of the output.
// out[0 .. N*N)      = tile(arange(N), N)  -> j % N
// out[N*N .. 2*N*N)  = repeat(arange(N),N) -> j / N
// Written as float values (output buffer is float32).
// ---------------------------------------------------------------------------
__global__ void edge_index_kernel(float* __restrict__ out) {
    const size_t half = (size_t)NN * NN; // 4194304
    size_t j4 = ((size_t)blockIdx.x * blockDim.x + threadIdx.x) * 4;
    float4 v;
    if (j4 < half) {
        v.x = (float)((j4 + 0) & (NN - 1));
        v.y = (float)((j4 + 1) & (NN - 1));
        v.z = (float)((j4 + 2) & (NN - 1));
        v.w = (float)((j4 + 3) & (NN - 1));
    } else {
        size_t p = j4 - half;            // p multiple of 4 -> all 4 share p>>11
        float g = (float)(p >> 11);
        v.x = g; v.y = g; v.z = g; v.w = g;
    }
    *reinterpret_cast<float4*>(out + j4) = v;
}

// ---------------------------------------------------------------------------
// Kernel 2: relaxed top-k subset sampling, one block per (b, row).
// 256 threads, each owns 8 columns: {4t..4t+3} and {1024+4t..1024+4t+3}.
// h = g / tau = 2*g kept in registers (exact, since tau = 0.5).
// ---------------------------------------------------------------------------
__global__ __launch_bounds__(256)
void relaxed_topk_kernel(const float* __restrict__ logits,
                         const float* __restrict__ gumbel,
                         float* __restrict__ out) {
    const int r    = blockIdx.x;
    const int b    = blockIdx.y;
    const int t    = threadIdx.x;
    const int lane = t & 63;
    const int wv   = t >> 6;

    __shared__ float sred[4];
    __shared__ int   sidx[4];

    const float* lrow = logits + (size_t)r * NN;
    const float* grow = gumbel + ((size_t)b * NN + r) * NN;

    float4 lv0 = *reinterpret_cast<const float4*>(lrow + 4 * t);
    float4 lv1 = *reinterpret_cast<const float4*>(lrow + 1024 + 4 * t);
    float4 gv0 = *reinterpret_cast<const float4*>(grow + 4 * t);
    float4 gv1 = *reinterpret_cast<const float4*>(grow + 1024 + 4 * t);

    float h[8];   // 2 * g
    float kh[8];  // accumulated khot
    {
        const float* lp0 = reinterpret_cast<const float*>(&lv0);
        const float* lp1 = reinterpret_cast<const float*>(&lv1);
        const float* gp0 = reinterpret_cast<const float*>(&gv0);
        const float* gp1 = reinterpret_cast<const float*>(&gv1);
        #pragma unroll
        for (int i = 0; i < 4; ++i) {
            float s0 = 5.0f * tanhf(lp0[i] / 5.0f);   // soft_clip, exact op order
            float s1 = 5.0f * tanhf(lp1[i] / 5.0f);
            h[i]     = 2.0f * (s0 + gp0[i]);
            h[i + 4] = 2.0f * (s1 + gp1[i]);
            kh[i] = 0.0f; kh[i + 4] = 0.0f;
        }
    }

    // ---- K iterations of masked softmax accumulation ----
    for (int k = 0; k < KSEL; ++k) {
        // block max(h)
        float m = h[0];
        #pragma unroll
        for (int i = 1; i < 8; ++i) m = fmaxf(m, h[i]);
        #pragma unroll
        for (int o = 32; o > 0; o >>= 1) m = fmaxf(m, __shfl_xor(m, o));
        if (lane == 0) sred[wv] = m;
        __syncthreads();
        m = fmaxf(fmaxf(sred[0], sred[1]), fmaxf(sred[2], sred[3]));
        __syncthreads();

        // exp + block sum
        float e[8];
        float s = 0.0f;
        #pragma unroll
        for (int i = 0; i < 8; ++i) { e[i] = expf(h[i] - m); s += e[i]; }
        #pragma unroll
        for (int o = 32; o > 0; o >>= 1) s += __shfl_xor(s, o);
        if (lane == 0) sred[wv] = s;
        __syncthreads();
        s = (sred[0] + sred[1]) + (sred[2] + sred[3]);
        __syncthreads();

        // onehot, khot accumulate, mask update (h += 2*log(clip(1-onehot,eps)))
        #pragma unroll
        for (int i = 0; i < 8; ++i) {
            float oh = e[i] / s;
            kh[i] += oh;
            h[i]  += 2.0f * logf(fmaxf(1.0f - oh, EPSV));
        }
    }

    // ---- top-K selection: 20 rounds of block argmax (tie -> lowest index) ----
    for (int k = 0; k < KSEL; ++k) {
        float bv = -1.0e30f;
        int   bi = NN;
        #pragma unroll
        for (int i = 0; i < 8; ++i) {
            int c = (i < 4) ? (4 * t + i) : (1024 + 4 * t + (i - 4));
            float v = kh[i];
            if (v > bv || (v == bv && c < bi)) { bv = v; bi = c; }
        }
        #pragma unroll
        for (int o = 32; o > 0; o >>= 1) {
            float ov = __shfl_xor(bv, o);
            int   oi = __shfl_xor(bi, o);
            if (ov > bv || (ov == bv && oi < bi)) { bv = ov; bi = oi; }
        }
        if (lane == 0) { sred[wv] = bv; sidx[wv] = bi; }
        __syncthreads();
        bv = sred[0]; bi = sidx[0];
        #pragma unroll
        for (int w = 1; w < 4; ++w) {
            float ov = sred[w]; int oi = sidx[w];
            if (ov > bv || (ov == bv && oi < bi)) { bv = ov; bi = oi; }
        }
        __syncthreads();
        // clear the winner (kh >= 0 always, so -1.0f is a safe sentinel)
        #pragma unroll
        for (int i = 0; i < 8; ++i) {
            int c = (i < 4) ? (4 * t + i) : (1024 + 4 * t + (i - 4));
            if (c == bi) kh[i] = -1.0f;
        }
    }

    // ---- write hard k-hot row ----
    float* orow = out + (size_t)2 * NN * NN + ((size_t)b * NN + r) * NN;
    float4 o0, o1;
    float* op0 = reinterpret_cast<float*>(&o0);
    float* op1 = reinterpret_cast<float*>(&o1);
    #pragma unroll
    for (int i = 0; i < 4; ++i) {
        op0[i] = (kh[i]     == -1.0f) ? 1.0f : 0.0f;
        op1[i] = (kh[i + 4] == -1.0f) ? 1.0f : 0.0f;
    }
    *reinterpret_cast<float4*>(orow + 4 * t)        = o0;
    *reinterpret_cast<float4*>(orow + 1024 + 4 * t) = o1;
}

// ---------------------------------------------------------------------------
extern "C" void kernel_launch(void* const* d_in, const int* in_sizes, int n_in,
                              void* d_out, int out_size, void* d_ws, size_t ws_size,
                              hipStream_t stream) {
    const float* logits = (const float*)d_in[0];  // [N, N]
    const float* gumbel = (const float*)d_in[1];  // [B, N, N]
    // d_in[2] (x) and d_in[3] (emb) do not affect the output.
    float* out = (float*)d_out;

    // edge_index: 2*N*N floats, 4 per thread
    const int ei_threads = (2 * NN * NN) / 4;             // 2097152
    edge_index_kernel<<<ei_threads / 256, 256, 0, stream>>>(out);

    dim3 grid(NN, BB);
    relaxed_topk_kernel<<<grid, 256, 0, stream>>>(logits, gumbel, out);
}

// Round 3
// 530.797 us; speedup vs baseline: 2.0088x; 2.0088x over previous
//
#include <hip/hip_runtime.h>
#include <cstdint>
#include <cstddef>

// Problem constants (match reference)
constexpr int    NN   = 2048;   // n_nodes
constexpr int    BB   = 8;      // n_samples
constexpr int    KSEL = 20;     // top-k
constexpr float  EPSV = 1e-20f; // clip epsilon
// TAU = 0.5 -> divide by tau == multiply by 2 (exact in fp32)

// ---------------------------------------------------------------------------
// Kernel 1: constant edge_index block of the output.
// ---------------------------------------------------------------------------
__global__ void edge_index_kernel(float* __restrict__ out) {
    const size_t half = (size_t)NN * NN; // 4194304
    size_t j4 = ((size_t)blockIdx.x * blockDim.x + threadIdx.x) * 4;
    float4 v;
    if (j4 < half) {
        v.x = (float)((j4 + 0) & (NN - 1));
        v.y = (float)((j4 + 1) & (NN - 1));
        v.z = (float)((j4 + 2) & (NN - 1));
        v.w = (float)((j4 + 3) & (NN - 1));
    } else {
        size_t p = j4 - half;
        float g = (float)(p >> 11);
        v.x = g; v.y = g; v.z = g; v.w = g;
    }
    *reinterpret_cast<float4*>(out + j4) = v;
}

// ---------------------------------------------------------------------------
// Kernel 2: relaxed top-k subset sampling, one block per (b, row).
// Multiplicative softmax-state: e <- e * q^2 replaces the reference's
// h += 2*log(q); e = exp(h - m) (scale-invariant, no overflow: e0 <= 2.6e14,
// sum <= 5e17, values only shrink).
// ---------------------------------------------------------------------------
__device__ __forceinline__ int colof(int t, int i) {
    return (i < 4) ? (4 * t + i) : (1024 + 4 * t + (i - 4));
}

__global__ __launch_bounds__(256)
void relaxed_topk_kernel(const float* __restrict__ logits,
                         const float* __restrict__ gumbel,
                         float* __restrict__ out) {
    const int r    = blockIdx.x;
    const int b    = blockIdx.y;
    const int t    = threadIdx.x;
    const int lane = t & 63;
    const int wv   = t >> 6;

    __shared__ float ssum[2][4];   // double-buffered wave partial sums
    __shared__ float swv[2][4];    // double-buffered wave argmax value
    __shared__ int   swi[2][4];    // double-buffered wave argmax index

    const float* lrow = logits + (size_t)r * NN;
    const float* grow = gumbel + ((size_t)b * NN + r) * NN;

    float4 lv0 = *reinterpret_cast<const float4*>(lrow + 4 * t);
    float4 lv1 = *reinterpret_cast<const float4*>(lrow + 1024 + 4 * t);
    float4 gv0 = *reinterpret_cast<const float4*>(grow + 4 * t);
    float4 gv1 = *reinterpret_cast<const float4*>(grow + 1024 + 4 * t);

    float e[8];   // unnormalized softmax numerator (multiplicative state)
    float kh[8];  // accumulated khot
    {
        const float* lp0 = reinterpret_cast<const float*>(&lv0);
        const float* lp1 = reinterpret_cast<const float*>(&lv1);
        const float* gp0 = reinterpret_cast<const float*>(&gv0);
        const float* gp1 = reinterpret_cast<const float*>(&gv1);
        #pragma unroll
        for (int i = 0; i < 4; ++i) {
            float s0 = 5.0f * tanhf(lp0[i] / 5.0f);   // soft_clip, exact op order
            float s1 = 5.0f * tanhf(lp1[i] / 5.0f);
            e[i]     = expf(2.0f * (s0 + gp0[i]));    // exp(h0); max-shift dropped
            e[i + 4] = expf(2.0f * (s1 + gp1[i]));    // (softmax is scale-invariant)
            kh[i] = 0.0f; kh[i + 4] = 0.0f;
        }
    }

    // ---- K iterations: s = sum(e); oh = e/s; kh += oh; e *= max(1-oh,eps)^2
    for (int k = 0; k < KSEL; ++k) {
        float s = ((e[0] + e[1]) + (e[2] + e[3])) + ((e[4] + e[5]) + (e[6] + e[7]));
        #pragma unroll
        for (int o = 32; o > 0; o >>= 1) s += __shfl_xor(s, o);
        if (lane == 0) ssum[k & 1][wv] = s;
        __syncthreads();
        float stot = (ssum[k & 1][0] + ssum[k & 1][1]) + (ssum[k & 1][2] + ssum[k & 1][3]);
        float inv = 1.0f / stot;
        #pragma unroll
        for (int i = 0; i < 8; ++i) {
            float oh = e[i] * inv;
            kh[i] += oh;
            float q = fmaxf(1.0f - oh, EPSV);
            e[i] *= q * q;
        }
        // no trailing barrier: next iteration writes the other ssum buffer,
        // and the k+2 reuse of this buffer is fenced by barrier k+1.
    }

    // ---- top-K: lazy per-wave argmax + cross-wave merge, 1 barrier/round ----
    float bv; int bi;
    {
        bv = -1.0e30f; bi = 1 << 30;
        #pragma unroll
        for (int i = 0; i < 8; ++i) {
            int c = colof(t, i);
            float v = kh[i];
            if (v > bv || (v == bv && c < bi)) { bv = v; bi = c; }
        }
        #pragma unroll
        for (int o = 32; o > 0; o >>= 1) {
            float ov = __shfl_xor(bv, o);
            int   oi = __shfl_xor(bi, o);
            if (ov > bv || (ov == bv && oi < bi)) { bv = ov; bi = oi; }
        }
    }
    if (lane == 0) { swv[0][wv] = bv; swi[0][wv] = bi; }
    __syncthreads();

    for (int k = 0; k < KSEL; ++k) {
        // pick global winner among the 4 cached wave maxima (uniform result)
        float gv = swv[k & 1][0]; int gi = swi[k & 1][0]; int gw = 0;
        #pragma unroll
        for (int w = 1; w < 4; ++w) {
            float v = swv[k & 1][w]; int ii = swi[k & 1][w];
            if (v > gv || (v == gv && ii < gi)) { gv = v; gi = ii; gw = w; }
        }
        if (wv == gw) {
            // winning wave: clear the winner column, recompute wave argmax
            #pragma unroll
            for (int i = 0; i < 8; ++i) {
                if (colof(t, i) == gi) kh[i] = -1.0f;   // kh >= 0, safe sentinel
            }
            bv = -1.0e30f; bi = 1 << 30;
            #pragma unroll
            for (int i = 0; i < 8; ++i) {
                int c = colof(t, i);
                float v = kh[i];
                if (v > bv || (v == bv && c < bi)) { bv = v; bi = c; }
            }
            #pragma unroll
            for (int o = 32; o > 0; o >>= 1) {
                float ov = __shfl_xor(bv, o);
                int   oi = __shfl_xor(bi, o);
                if (ov > bv || (ov == bv && oi < bi)) { bv = ov; bi = oi; }
            }
        }
        // every wave republishes its (possibly cached) argmax into the next buffer
        if (lane == 0) { swv[(k + 1) & 1][wv] = bv; swi[(k + 1) & 1][wv] = bi; }
        __syncthreads();
    }

    // ---- write hard k-hot row ----
    float* orow = out + (size_t)2 * NN * NN + ((size_t)b * NN + r) * NN;
    float4 o0, o1;
    float* op0 = reinterpret_cast<float*>(&o0);
    float* op1 = reinterpret_cast<float*>(&o1);
    #pragma unroll
    for (int i = 0; i < 4; ++i) {
        op0[i] = (kh[i]     == -1.0f) ? 1.0f : 0.0f;
        op1[i] = (kh[i + 4] == -1.0f) ? 1.0f : 0.0f;
    }
    *reinterpret_cast<float4*>(orow + 4 * t)        = o0;
    *reinterpret_cast<float4*>(orow + 1024 + 4 * t) = o1;
}

// ---------------------------------------------------------------------------
extern "C" void kernel_launch(void* const* d_in, const int* in_sizes, int n_in,
                              void* d_out, int out_size, void* d_ws, size_t ws_size,
                              hipStream_t stream) {
    const float* logits = (const float*)d_in[0];  // [N, N]
    const float* gumbel = (const float*)d_in[1];  // [B, N, N]
    // d_in[2] (x) and d_in[3] (emb) do not affect the output.
    float* out = (float*)d_out;

    const int ei_threads = (2 * NN * NN) / 4;
    edge_index_kernel<<<ei_threads / 256, 256, 0, stream>>>(out);

    dim3 grid(NN, BB);
    relaxed_topk_kernel<<<grid, 256, 0, stream>>>(logits, gumbel, out);
}

// Round 4
// 517.114 us; speedup vs baseline: 2.0619x; 1.0265x over previous
//
#include <hip/hip_runtime.h>
#include <cstdint>
#include <cstddef>

// Problem constants (match reference)
constexpr int    NN   = 2048;   // n_nodes
constexpr int    BB   = 8;      // n_samples
constexpr int    KSEL = 20;     // top-k
// TAU = 0.5 -> divide by tau == multiply by 2 (exact in fp32)

typedef float v2f __attribute__((ext_vector_type(2)));

// --- packed f32 math (VOP3P, 2 lanes of f32 per instruction) ---
__device__ __forceinline__ v2f pk_fma(v2f a, v2f b, v2f c) {
    v2f d;
    asm("v_pk_fma_f32 %0, %1, %2, %3" : "=v"(d) : "v"(a), "v"(b), "v"(c));
    return d;
}
__device__ __forceinline__ v2f pk_mul(v2f a, v2f b) {
    v2f d;
    asm("v_pk_mul_f32 %0, %1, %2" : "=v"(d) : "v"(a), "v"(b));
    return d;
}
__device__ __forceinline__ v2f pk_add(v2f a, v2f b) {
    v2f d;
    asm("v_pk_add_f32 %0, %1, %2" : "=v"(d) : "v"(a), "v"(b));
    return d;
}

__device__ __forceinline__ int colof(int t, int i) {
    return (i < 4) ? (4 * t + i) : (1024 + 4 * t + (i - 4));
}

// ---------------------------------------------------------------------------
// One block per (b, row). 256 threads, 8 columns/thread as 4x float2.
// Multiplicative softmax-state: e <- e * (1 - e/s)^2 replaces the reference's
// h += 2*log(clip(1-oh,eps)); e = exp(h - m). Scale-invariant; e0 <= 2.1e18,
// sum <= 4.3e21, values only shrink -> no overflow, no max-subtract needed.
// eps clamp dropped: q rounding to 0 (or tiny negative; q is squared) crushes
// e to ~0, same selection outcome as the reference's exp(-92) path.
// Each block also writes its 512-float slice of the constant edge_index.
// ---------------------------------------------------------------------------
__global__ __launch_bounds__(256)
void relaxed_topk_kernel(const float* __restrict__ logits,
                         const float* __restrict__ gumbel,
                         float* __restrict__ out) {
    const int r    = blockIdx.x;
    const int b    = blockIdx.y;
    const int t    = threadIdx.x;
    const int lane = t & 63;
    const int wv   = t >> 6;

    __shared__ float ssum[2][4];   // double-buffered wave partial sums
    __shared__ float swv[2][4];    // double-buffered wave argmax value
    __shared__ int   swi[2][4];    // double-buffered wave argmax index

    // ---- constant edge_index slice (independent of inputs) ----
    {
        const int L    = b * NN + r;          // 0..16383; 16384*512 = 2*N*N
        const int base = L * 512 + 2 * t;
        float2 w;
        if (L < 8192) {                        // tile(arange(N), N) -> j & 2047
            w.x = (float)(base & (NN - 1));
            w.y = (float)((base + 1) & (NN - 1));
        } else {                               // repeat(arange(N), N) -> p >> 11
            float v = (float)((L - 8192) >> 2);  // slice never crosses a row
            w.x = v; w.y = v;
        }
        *reinterpret_cast<float2*>(out + base) = w;
    }

    const float* lrow = logits + (size_t)r * NN;
    const float* grow = gumbel + ((size_t)b * NN + r) * NN;

    float4 lv0 = *reinterpret_cast<const float4*>(lrow + 4 * t);
    float4 lv1 = *reinterpret_cast<const float4*>(lrow + 1024 + 4 * t);
    float4 gv0 = *reinterpret_cast<const float4*>(grow + 4 * t);
    float4 gv1 = *reinterpret_cast<const float4*>(grow + 1024 + 4 * t);

    v2f e2[4];   // unnormalized softmax numerator (multiplicative state)
    v2f kh2[4];  // accumulated khot
    {
        const float* lp0 = reinterpret_cast<const float*>(&lv0);
        const float* lp1 = reinterpret_cast<const float*>(&lv1);
        const float* gp0 = reinterpret_cast<const float*>(&gv0);
        const float* gp1 = reinterpret_cast<const float*>(&gv1);
        float ei[8];
        #pragma unroll
        for (int i = 0; i < 4; ++i) {
            // soft_clip: 5*tanh(l/5) = 5*(E-1)/(E+1), E = exp(0.4*l)
            float E0 = __expf(0.4f * lp0[i]);
            float E1 = __expf(0.4f * lp1[i]);
            float s0 = 5.0f * (E0 - 1.0f) * __builtin_amdgcn_rcpf(E0 + 1.0f);
            float s1 = 5.0f * (E1 - 1.0f) * __builtin_amdgcn_rcpf(E1 + 1.0f);
            ei[i]     = __expf(2.0f * (s0 + gp0[i]));   // exp(h0), no max-shift
            ei[i + 4] = __expf(2.0f * (s1 + gp1[i]));
        }
        e2[0] = v2f{ei[0], ei[1]};  e2[1] = v2f{ei[2], ei[3]};
        e2[2] = v2f{ei[4], ei[5]};  e2[3] = v2f{ei[6], ei[7]};
        kh2[0] = v2f{0.f, 0.f}; kh2[1] = v2f{0.f, 0.f};
        kh2[2] = v2f{0.f, 0.f}; kh2[3] = v2f{0.f, 0.f};
    }

    // ---- K iterations: s=sum(e); kh+=e/s; e*=(1-e/s)^2 — packed f32 ----
    for (int k = 0; k < KSEL; ++k) {
        v2f s2 = pk_add(pk_add(e2[0], e2[1]), pk_add(e2[2], e2[3]));
        float s = s2.x + s2.y;
        #pragma unroll
        for (int o = 32; o > 0; o >>= 1) s += __shfl_xor(s, o);
        if (lane == 0) ssum[k & 1][wv] = s;
        __syncthreads();
        float stot = (ssum[k & 1][0] + ssum[k & 1][1]) + (ssum[k & 1][2] + ssum[k & 1][3]);
        float inv = __builtin_amdgcn_rcpf(stot);
        v2f inv2  = v2f{inv, inv};
        v2f ninv2 = v2f{-inv, -inv};
        v2f one2  = v2f{1.0f, 1.0f};
        #pragma unroll
        for (int i = 0; i < 4; ++i) {
            kh2[i] = pk_fma(e2[i], inv2, kh2[i]);     // kh += e/s
            v2f q  = pk_fma(e2[i], ninv2, one2);      // q = 1 - e/s
            e2[i]  = pk_mul(e2[i], pk_mul(q, q));     // e *= q^2
        }
        // next iteration writes the other ssum buffer; k+2 reuse fenced by k+1
    }

    // ---- unpack for top-k ----
    float kh[8];
    kh[0] = kh2[0].x; kh[1] = kh2[0].y; kh[2] = kh2[1].x; kh[3] = kh2[1].y;
    kh[4] = kh2[2].x; kh[5] = kh2[2].y; kh[6] = kh2[3].x; kh[7] = kh2[3].y;

    // ---- top-K: lazy per-wave argmax + cross-wave merge, 1 barrier/round ----
    float bv; int bi;
    {
        bv = -1.0e30f; bi = 1 << 30;
        #pragma unroll
        for (int i = 0; i < 8; ++i) {
            int c = colof(t, i);
            float v = kh[i];
            if (v > bv || (v == bv && c < bi)) { bv = v; bi = c; }
        }
        #pragma unroll
        for (int o = 32; o > 0; o >>= 1) {
            float ov = __shfl_xor(bv, o);
            int   oi = __shfl_xor(bi, o);
            if (ov > bv || (ov == bv && oi < bi)) { bv = ov; bi = oi; }
        }
    }
    if (lane == 0) { swv[0][wv] = bv; swi[0][wv] = bi; }
    __syncthreads();

    for (int k = 0; k < KSEL; ++k) {
        float gmv = swv[k & 1][0]; int gi = swi[k & 1][0]; int gw = 0;
        #pragma unroll
        for (int w = 1; w < 4; ++w) {
            float v = swv[k & 1][w]; int ii = swi[k & 1][w];
            if (v > gmv || (v == gmv && ii < gi)) { gmv = v; gi = ii; gw = w; }
        }
        if (wv == gw) {
            #pragma unroll
            for (int i = 0; i < 8; ++i) {
                if (colof(t, i) == gi) kh[i] = -1.0f;   // kh >= 0, safe sentinel
            }
            bv = -1.0e30f; bi = 1 << 30;
            #pragma unroll
            for (int i = 0; i < 8; ++i) {
                int c = colof(t, i);
                float v = kh[i];
                if (v > bv || (v == bv && c < bi)) { bv = v; bi = c; }
            }
            #pragma unroll
            for (int o = 32; o > 0; o >>= 1) {
                float ov = __shfl_xor(bv, o);
                int   oi = __shfl_xor(bi, o);
                if (ov > bv || (ov == bv && oi < bi)) { bv = ov; bi = oi; }
            }
        }
        if (lane == 0) { swv[(k + 1) & 1][wv] = bv; swi[(k + 1) & 1][wv] = bi; }
        __syncthreads();
    }

    // ---- write hard k-hot row ----
    float* orow = out + (size_t)2 * NN * NN + ((size_t)b * NN + r) * NN;
    float4 o0, o1;
    float* op0 = reinterpret_cast<float*>(&o0);
    float* op1 = reinterpret_cast<float*>(&o1);
    #pragma unroll
    for (int i = 0; i < 4; ++i) {
        op0[i] = (kh[i]     == -1.0f) ? 1.0f : 0.0f;
        op1[i] = (kh[i + 4] == -1.0f) ? 1.0f : 0.0f;
    }
    *reinterpret_cast<float4*>(orow + 4 * t)        = o0;
    *reinterpret_cast<float4*>(orow + 1024 + 4 * t) = o1;
}

// ---------------------------------------------------------------------------
extern "C" void kernel_launch(void* const* d_in, const int* in_sizes, int n_in,
                              void* d_out, int out_size, void* d_ws, size_t ws_size,
                              hipStream_t stream) {
    const float* logits = (const float*)d_in[0];  // [N, N]
    const float* gumbel = (const float*)d_in[1];  // [B, N, N]
    // d_in[2] (x) and d_in[3] (emb) do not affect the output.
    float* out = (float*)d_out;

    dim3 grid(NN, BB);
    relaxed_topk_kernel<<<grid, 256, 0, stream>>>(logits, gumbel, out);
}

// Round 5
// 363.850 us; speedup vs baseline: 2.9304x; 1.4212x over previous
//
#include <hip/hip_runtime.h>
#include <cstdint>
#include <cstddef>

// Problem constants (match reference)
constexpr int NN   = 2048;  // n_nodes
constexpr int BB   = 8;     // n_samples
constexpr int KSEL = 20;    // top-k
// TAU = 0.5 -> divide by tau == multiply by 2 (exact in fp32)

typedef float v2f __attribute__((ext_vector_type(2)));

// --- packed f32 math (VOP3P, 2 lanes of f32 per instruction) ---
__device__ __forceinline__ v2f pk_fma(v2f a, v2f b, v2f c) {
    v2f d; asm("v_pk_fma_f32 %0, %1, %2, %3" : "=v"(d) : "v"(a), "v"(b), "v"(c)); return d;
}
__device__ __forceinline__ v2f pk_mul(v2f a, v2f b) {
    v2f d; asm("v_pk_mul_f32 %0, %1, %2" : "=v"(d) : "v"(a), "v"(b)); return d;
}
__device__ __forceinline__ v2f pk_add(v2f a, v2f b) {
    v2f d; asm("v_pk_add_f32 %0, %1, %2" : "=v"(d) : "v"(a), "v"(b)); return d;
}

// --- DPP wave64 reductions (pure VALU pipe; no LDS, no barriers) ---
// ctrl: row_shr:N = 0x110+N, ROW_BCAST15 = 0x142, ROW_BCAST31 = 0x143.
// After shr1/2/4/8 + bcast15 + bcast31, lane 63 holds the full-wave result.
template <int CTRL>
__device__ __forceinline__ float dpp_add_step(float x) {
    int y = __builtin_amdgcn_update_dpp(0, __float_as_int(x), CTRL, 0xf, 0xf, false);
    return x + __int_as_float(y);  // old = 0 -> sourceless lanes add identity
}
__device__ __forceinline__ float wave_sum(float x) {
    x = dpp_add_step<0x111>(x);
    x = dpp_add_step<0x112>(x);
    x = dpp_add_step<0x114>(x);
    x = dpp_add_step<0x118>(x);
    x = dpp_add_step<0x142>(x);
    x = dpp_add_step<0x143>(x);
    return __int_as_float(__builtin_amdgcn_readlane(__float_as_int(x), 63));
}
template <int CTRL>
__device__ __forceinline__ void dpp_amax_step(float& v, int& c) {
    // old = (-inf, INT_MAX): sourceless lanes can never win
    float ov = __int_as_float(__builtin_amdgcn_update_dpp(
        (int)0xFF800000, __float_as_int(v), CTRL, 0xf, 0xf, false));
    int oc = __builtin_amdgcn_update_dpp(0x7FFFFFFF, c, CTRL, 0xf, 0xf, false);
    if (ov > v || (ov == v && oc < c)) { v = ov; c = oc; }
}
__device__ __forceinline__ int wave_argmax_col(float v, int c) {
    dpp_amax_step<0x111>(v, c);
    dpp_amax_step<0x112>(v, c);
    dpp_amax_step<0x114>(v, c);
    dpp_amax_step<0x118>(v, c);
    dpp_amax_step<0x142>(v, c);
    dpp_amax_step<0x143>(v, c);
    return __builtin_amdgcn_readlane(c, 63);   // uniform (SGPR) winner column
}

// ---------------------------------------------------------------------------
// One WAVE per (b, row): 64 lanes x 32 cols, col(q,j) = q*256 + 4*lane + j,
// stored as e2/kh2[2q + (j>>1)] .x/.y. Zero __syncthreads, zero LDS.
// Multiplicative softmax-state: e <- e * (1 - e/s)^2 (scale-invariant;
// e0 <= 2.1e18, sum <= 4.3e21 -> no overflow; q^2 >= 0 so clamp-free).
// Each block also writes its 2048-float slice of the constant edge_index.
// ---------------------------------------------------------------------------
__global__ __launch_bounds__(256)
void relaxed_topk_wave(const float* __restrict__ logits,
                       const float* __restrict__ gumbel,
                       float* __restrict__ out) {
    const int t    = threadIdx.x;
    const int lane = t & 63;
    const int wv   = t >> 6;
    const int r    = blockIdx.x * 4 + wv;   // gridDim.x = 512
    const int b    = blockIdx.y;

    // ---- constant edge_index slice (4096 blocks x 2048 floats) ----
    {
        const int F = blockIdx.y * 512 + blockIdx.x;          // 0..4095
        float* base = out + (size_t)F * 2048 + t * 8;
        float4 w0, w1;
        if (F < 2048) {   // first half: out[j] = j & 2047 -> t*8 + i
            float m = (float)(t * 8);
            w0 = make_float4(m, m + 1.0f, m + 2.0f, m + 3.0f);
            w1 = make_float4(m + 4.0f, m + 5.0f, m + 6.0f, m + 7.0f);
        } else {          // second half: out[N*N + p] = p >> 11 -> F - 2048
            float v = (float)(F - 2048);
            w0 = make_float4(v, v, v, v); w1 = w0;
        }
        *reinterpret_cast<float4*>(base)     = w0;
        *reinterpret_cast<float4*>(base + 4) = w1;
    }

    const float* lrow = logits + (size_t)r * NN;
    const float* grow = gumbel + ((size_t)b * NN + r) * NN;
    const int c0 = 4 * lane;

    v2f e2[16];   // unnormalized softmax numerator (multiplicative state)
    v2f kh2[16];  // accumulated khot
    #pragma unroll
    for (int q = 0; q < 8; ++q) {
        float4 lv = *reinterpret_cast<const float4*>(lrow + q * 256 + c0);
        float4 gv = *reinterpret_cast<const float4*>(grow + q * 256 + c0);
        const float* lp = reinterpret_cast<const float*>(&lv);
        const float* gp = reinterpret_cast<const float*>(&gv);
        float ei[4];
        #pragma unroll
        for (int j = 0; j < 4; ++j) {
            // soft_clip: 5*tanh(l/5) = 5*(E-1)/(E+1), E = exp(0.4*l)
            float E  = __expf(0.4f * lp[j]);
            float sc = 5.0f * (E - 1.0f) * __builtin_amdgcn_rcpf(E + 1.0f);
            ei[j] = __expf(2.0f * (sc + gp[j]));   // exp(h0); no max-shift needed
        }
        e2[2 * q]     = v2f{ei[0], ei[1]};
        e2[2 * q + 1] = v2f{ei[2], ei[3]};
        kh2[2 * q]     = v2f{0.0f, 0.0f};
        kh2[2 * q + 1] = v2f{0.0f, 0.0f};
    }

    // ---- K iterations: s = sum(e); kh += e/s; e *= (1 - e/s)^2 ----
    for (int k = 0; k < KSEL; ++k) {
        v2f a0 = pk_add(pk_add(e2[0],  e2[1]),  pk_add(e2[2],  e2[3]));
        v2f a1 = pk_add(pk_add(e2[4],  e2[5]),  pk_add(e2[6],  e2[7]));
        v2f a2 = pk_add(pk_add(e2[8],  e2[9]),  pk_add(e2[10], e2[11]));
        v2f a3 = pk_add(pk_add(e2[12], e2[13]), pk_add(e2[14], e2[15]));
        v2f aa = pk_add(pk_add(a0, a1), pk_add(a2, a3));
        float stot = wave_sum(aa.x + aa.y);
        float inv  = __builtin_amdgcn_rcpf(stot);
        v2f inv2  = v2f{inv, inv};
        v2f ninv2 = v2f{-inv, -inv};
        v2f one2  = v2f{1.0f, 1.0f};
        #pragma unroll
        for (int i = 0; i < 16; ++i) {
            kh2[i] = pk_fma(e2[i], inv2, kh2[i]);   // kh += e/s
            v2f q2 = pk_fma(e2[i], ninv2, one2);    // q  = 1 - e/s
            e2[i]  = pk_mul(e2[i], pk_mul(q2, q2)); // e *= q^2
        }
    }

    // ---- top-K: per-lane group maxima (4 groups x 8 elems) + DPP argmax ----
    float gvmax[4]; int gcmax[4];
    #pragma unroll
    for (int g = 0; g < 4; ++g) {
        float bv = -1.0f; int bc = 1 << 30;        // kh >= 0 always
        #pragma unroll
        for (int q = 2 * g; q < 2 * g + 2; ++q) {
            #pragma unroll
            for (int h = 0; h < 2; ++h) {
                float vx = kh2[2 * q + h].x, vy = kh2[2 * q + h].y;
                int   cx = q * 256 + c0 + 2 * h, cy = cx + 1;
                if (vx > bv || (vx == bv && cx < bc)) { bv = vx; bc = cx; }
                if (vy > bv || (vy == bv && cy < bc)) { bv = vy; bc = cy; }
            }
        }
        gvmax[g] = bv; gcmax[g] = bc;
    }

    for (int k = 0; k < KSEL; ++k) {
        float bv = gvmax[0]; int bc = gcmax[0];
        #pragma unroll
        for (int g = 1; g < 4; ++g) {
            if (gvmax[g] > bv || (gvmax[g] == bv && gcmax[g] < bc)) {
                bv = gvmax[g]; bc = gcmax[g];
            }
        }
        const int gi = wave_argmax_col(bv, bc);    // uniform winner column
        const int gg = gi >> 9;                    // affected group (uniform)
        // clear winner elem + rescan only the affected group (scalar branch)
        #pragma unroll
        for (int G = 0; G < 4; ++G) {
            if (gg == G) {
                float bv2 = -1.0f; int bc2 = 1 << 30;
                #pragma unroll
                for (int q = 2 * G; q < 2 * G + 2; ++q) {
                    #pragma unroll
                    for (int h = 0; h < 2; ++h) {
                        int cx = q * 256 + c0 + 2 * h, cy = cx + 1;
                        if (cx == gi) kh2[2 * q + h].x = -1.0f;   // selected marker
                        if (cy == gi) kh2[2 * q + h].y = -1.0f;
                        float vx = kh2[2 * q + h].x, vy = kh2[2 * q + h].y;
                        if (vx > bv2 || (vx == bv2 && cx < bc2)) { bv2 = vx; bc2 = cx; }
                        if (vy > bv2 || (vy == bv2 && cy < bc2)) { bv2 = vy; bc2 = cy; }
                    }
                }
                gvmax[G] = bv2; gcmax[G] = bc2;
            }
        }
    }

    // ---- write hard k-hot row (marker kh == -1 -> 1.0) ----
    float* orow = out + (size_t)2 * NN * NN + ((size_t)b * NN + r) * NN;
    #pragma unroll
    for (int q = 0; q < 8; ++q) {
        float4 o;
        o.x = (kh2[2 * q].x     == -1.0f) ? 1.0f : 0.0f;
        o.y = (kh2[2 * q].y     == -1.0f) ? 1.0f : 0.0f;
        o.z = (kh2[2 * q + 1].x == -1.0f) ? 1.0f : 0.0f;
        o.w = (kh2[2 * q + 1].y == -1.0f) ? 1.0f : 0.0f;
        *reinterpret_cast<float4*>(orow + q * 256 + c0) = o;
    }
}

// ---------------------------------------------------------------------------
extern "C" void kernel_launch(void* const* d_in, const int* in_sizes, int n_in,
                              void* d_out, int out_size, void* d_ws, size_t ws_size,
                              hipStream_t stream) {
    const float* logits = (const float*)d_in[0];  // [N, N]
    const float* gumbel = (const float*)d_in[1];  // [B, N, N]
    // d_in[2] (x) and d_in[3] (emb) do not affect the output.
    float* out = (float*)d_out;

    dim3 grid(NN / 4, BB);   // one wave per (b, row); 4 waves per block
    relaxed_topk_wave<<<grid, 256, 0, stream>>>(logits, gumbel, out);
}